// Round 3
// baseline (136.998 us; speedup 1.0000x reference)
//
#include <hip/hip_runtime.h>

#define N_TOT 8192
#define NS 4096
#define D 256
#define NB 64                 // 8192/128 tiles per dim
#define NTRI (NB*(NB+1)/2)    // 2080 upper-triangle tiles
#define HALF_B 32             // tiles per half (4096/128)

typedef float f32x16 __attribute__((ext_vector_type(16)));
typedef short bf16x8 __attribute__((ext_vector_type(8)));

// fp32 -> bf16 bits, round-to-nearest-even
__device__ __forceinline__ unsigned short f2bf(float f) {
  unsigned int u = __builtin_bit_cast(unsigned int, f);
  u += 0x7FFFu + ((u >> 16) & 1u);
  return (unsigned short)(u >> 16);
}

// ---- K1: one pass over inputs ----
// Writes X in MFMA-fragment-packed bf16 layout:
//   P[panel(row>>5)][chunk(col>>4)][half((col>>3)&1)][m(row&31)][j(col&7)]
// so a wave's 64 lanes read one fragment as 1024 contiguous bytes.
// Also: row sq-norms (fp32), per-block column partial sums.
__global__ void k_prep(const float* __restrict__ src, const float* __restrict__ tgt,
                       unsigned short* __restrict__ P, float* __restrict__ sqv,
                       float* __restrict__ pm) {
  __shared__ float colacc[256];
  int t = threadIdx.x, l = t & 63, w = t >> 6;
  colacc[t] = 0.f;
  __syncthreads();
  int base = blockIdx.x * 32;
  int chunk = l >> 2, half = (l >> 1) & 1, j0 = (l & 1) * 4;  // cols 4l..4l+3
  float c0 = 0.f, c1 = 0.f, c2 = 0.f, c3 = 0.f;
  #pragma unroll
  for (int r = 0; r < 8; ++r) {
    int row = base + w * 8 + r;
    const float* p = (row < NS) ? (src + (size_t)row * D) : (tgt + (size_t)(row - NS) * D);
    float4 v = ((const float4*)p)[l];
    ushort4 bv;
    bv.x = f2bf(v.x); bv.y = f2bf(v.y); bv.z = f2bf(v.z); bv.w = f2bf(v.w);
    size_t off = (size_t)(row >> 5) * 8192 + chunk * 512 + half * 256 + (row & 31) * 8 + j0;
    *(ushort4*)(P + off) = bv;
    c0 += v.x; c1 += v.y; c2 += v.z; c3 += v.w;
    float s = fmaf(v.x, v.x, fmaf(v.y, v.y, fmaf(v.z, v.z, v.w * v.w)));
    for (int o = 32; o > 0; o >>= 1) s += __shfl_down(s, o, 64);
    if (l == 0) sqv[row] = s;
  }
  atomicAdd(&colacc[4 * l + 0], c0);
  atomicAdd(&colacc[4 * l + 1], c1);
  atomicAdd(&colacc[4 * l + 2], c2);
  atomicAdd(&colacc[4 * l + 3], c3);
  __syncthreads();
  pm[blockIdx.x * 256 + t] = colacc[t];
}

// ---- K2: finalize bandwidth in fp64; zero the completion counter ----
__global__ void k_bw(const float* __restrict__ pm, const float* __restrict__ sqv,
                     float* __restrict__ coef, int* __restrict__ cnt) {
  __shared__ double red[256];
  int t = threadIdx.x;
  float cs = 0.f;
  for (int b = 0; b < 256; ++b) cs += pm[b * 256 + t];
  red[t] = (double)cs * (double)cs;
  __syncthreads();
  for (int s = 128; s > 0; s >>= 1) {
    if (t < s) red[t] += red[t + s];
    __syncthreads();
  }
  double msq = red[0];
  __syncthreads();
  double ss = 0.0;
  for (int k = 0; k < 32; ++k) ss += (double)sqv[t + 256 * k];
  red[t] = ss;
  __syncthreads();
  for (int s = 128; s > 0; s >>= 1) {
    if (t < s) red[t] += red[t + s];
    __syncthreads();
  }
  if (t == 0) {
    double S = red[0];
    double n = (double)N_TOT;
    double sumL2 = 2.0 * n * S - 2.0 * msq;
    double bw = sumL2 / (n * n - n) / 4.0;        // / KERNEL_MUL**(KERNEL_NUM//2)
    double c4 = 1.0 / (bw * 16.0 + 1e-6);         // widest kernel (k=4)
    coef[0] = (float)(c4 * 1.4426950408889634);   // * log2(e) for exp2
    cnt[0] = 0;
  }
}

// ---- K3: upper-triangle 128x128 tiles, LDS-free: fragments straight from packed X ----
__global__ __launch_bounds__(256) void k_main(
    const unsigned short* __restrict__ P, const float* __restrict__ sqv,
    const float* __restrict__ coef, float* __restrict__ bpart,
    int* __restrict__ cnt, float* __restrict__ out) {
  // triangular decode: block b -> (bi, bj), bi <= bj
  int b = blockIdx.x;
  int bi = (int)((2.f * NB + 1.f - sqrtf((float)((2 * NB + 1) * (2 * NB + 1) - 8 * b))) * 0.5f);
  if (bi < 0) bi = 0;
  if (bi > NB - 1) bi = NB - 1;
  while ((bi + 1) * (2 * NB - bi) / 2 <= b) ++bi;
  while (bi * (2 * NB - bi + 1) / 2 > b) --bi;
  int bj = bi + (b - bi * (2 * NB - bi + 1) / 2);

  __shared__ float sqA[128], sqB[128];
  __shared__ float redw[4];
  __shared__ double red[256];
  __shared__ int lastFlag;

  int t = threadIdx.x, l = t & 63, w = t >> 6;
  int lr = l & 31, half = l >> 5;
  int waveRow = w >> 1, waveCol = w & 1;

  if (t < 128) sqA[t] = sqv[bi * 128 + t];
  else         sqB[t - 128] = sqv[bj * 128 + (t - 128)];
  float A4 = coef[0];

  // panel = 32 rows; block covers A panels bi*4..+3, B panels bj*4..+3
  // fragment for (panel, chunk c): bf16x8 at P + panel*8192 + c*512 + l*8 (ushorts)
  const bf16x8* Pf = (const bf16x8*)P;  // panel stride 1024, chunk stride 64 (in bf16x8)
  int pa0 = bi * 4 + waveRow * 2;
  int pb0 = bj * 4 + waveCol * 2;
  const bf16x8* ap0 = Pf + (size_t)pa0 * 1024 + l;
  const bf16x8* ap1 = Pf + (size_t)(pa0 + 1) * 1024 + l;
  const bf16x8* bp0 = Pf + (size_t)pb0 * 1024 + l;
  const bf16x8* bp1 = Pf + (size_t)(pb0 + 1) * 1024 + l;

  f32x16 acc[2][2] = {};
  #pragma unroll 2
  for (int c = 0; c < 16; ++c) {
    bf16x8 aF0 = ap0[c * 64];
    bf16x8 aF1 = ap1[c * 64];
    bf16x8 bF0 = bp0[c * 64];
    bf16x8 bF1 = bp1[c * 64];
    acc[0][0] = __builtin_amdgcn_mfma_f32_32x32x16_bf16(aF0, bF0, acc[0][0], 0, 0, 0);
    acc[0][1] = __builtin_amdgcn_mfma_f32_32x32x16_bf16(aF0, bF1, acc[0][1], 0, 0, 0);
    acc[1][0] = __builtin_amdgcn_mfma_f32_32x32x16_bf16(aF1, bF0, acc[1][0], 0, 0, 0);
    acc[1][1] = __builtin_amdgcn_mfma_f32_32x32x16_bf16(aF1, bF1, acc[1][1], 0, 0, 0);
  }

  // Epilogue: L2 -> e = exp2(-L2*c4*log2e); sum5 = e+e^2+e^4+e^8+e^16
  // C/D layout (verified): col = lane&31, row = (r&3) + 8*(r>>2) + 4*(lane>>5)
  float lsum = 0.f;
  bool diag = (bi == bj);
  #pragma unroll
  for (int cb = 0; cb < 2; ++cb) {
    int jj = waveCol * 64 + cb * 32 + lr;
    float sqj = sqB[jj];
    #pragma unroll
    for (int rb = 0; rb < 2; ++rb) {
      #pragma unroll
      for (int r = 0; r < 16; ++r) {
        int ii = waveRow * 64 + rb * 32 + (r & 3) + 8 * (r >> 2) + 4 * half;
        float sqi = sqA[ii];
        float dot = acc[rb][cb][r];
        float l2 = fmaf(-2.f, dot, sqi + sqj);
        float e = __builtin_amdgcn_exp2f(-l2 * A4);
        float e2 = e * e, e4 = e2 * e2, e8 = e4 * e4, e16 = e8 * e8;
        float kern = ((e + e2) + (e4 + e8)) + e16;
        if (diag) kern = (ii == jj) ? 0.f : kern;  // diagonal handled analytically
        lsum += kern;
      }
    }
  }
  for (int o = 32; o > 0; o >>= 1) lsum += __shfl_down(lsum, o, 64);
  if (l == 0) redw[w] = lsum;
  __syncthreads();
  if (t == 0) {
    float tot = (redw[0] + redw[1]) + (redw[2] + redw[3]);
    float wgt = diag ? 1.f : 2.f;                               // symmetry weight
    float sgn = ((bi < HALF_B) == (bj < HALF_B)) ? 1.f : -1.f;  // s_i * s_j
    bpart[b] = tot * wgt * sgn;
    __threadfence();                                            // publish bpart[b]
    int old = atomicAdd(cnt, 1);
    lastFlag = (old == NTRI - 1);
  }
  __syncthreads();
  if (lastFlag) {                 // last block to finish: final fp64 reduction
    __threadfence();              // acquire: make all bpart writes visible
    double s = 0.0;
    for (int k = 0; k < 9; ++k) {
      int idx = k * 256 + t;
      if (idx < NTRI) s += (double)bpart[idx];
    }
    red[t] = s;
    __syncthreads();
    for (int st = 128; st > 0; st >>= 1) {
      if (t < st) red[t] += red[t + st];
      __syncthreads();
    }
    if (t == 0) {
      double total = red[0] + 5.0 * (double)N_TOT;  // diagonal: K_ii = 5, sign +1
      out[0] = (float)(total / ((double)NS * (double)NS));
    }
  }
}

extern "C" void kernel_launch(void* const* d_in, const int* in_sizes, int n_in,
                              void* d_out, int out_size, void* d_ws, size_t ws_size,
                              hipStream_t stream) {
  const float* src = (const float*)d_in[0];
  const float* tgt = (const float*)d_in[1];
  float* out = (float*)d_out;
  char* ws = (char*)d_ws;
  unsigned short* P = (unsigned short*)ws;                      // 4 MB packed bf16
  float* sqv  = (float*)(ws + (4u << 20));                      // 32 KB row sq-norms
  float* pm   = (float*)(ws + (4u << 20) + (32u << 10));        // 256 KB col partials
  float* coef = (float*)(ws + (4u << 20) + (288u << 10));       // 4 B
  int*   cnt  = (int*)  (ws + (4u << 20) + (288u << 10) + 64);  // 4 B completion counter
  float* bpart = (float*)(ws + (4u << 20) + (289u << 10));      // 8.3 KB tile partials

  hipLaunchKernelGGL(k_prep, dim3(256), dim3(256), 0, stream, src, tgt, P, sqv, pm);
  hipLaunchKernelGGL(k_bw, dim3(1), dim3(256), 0, stream, pm, sqv, coef, cnt);
  hipLaunchKernelGGL(k_main, dim3(NTRI), dim3(256), 0, stream, P, sqv, coef, bpart, cnt, out);
}

// Round 4
// 129.633 us; speedup vs baseline: 1.0568x; 1.0568x over previous
//
#include <hip/hip_runtime.h>

#define N_TOT 8192
#define NS 4096
#define D 256
#define NB 64                 // 8192/128 tiles per dim
#define NTRI (NB*(NB+1)/2)    // 2080 upper-triangle tiles
#define HALF_B 32             // tiles per half (4096/128)

typedef float f32x16 __attribute__((ext_vector_type(16)));
typedef float f32x2 __attribute__((ext_vector_type(2)));
typedef short bf16x8 __attribute__((ext_vector_type(8)));

__device__ __forceinline__ void gload16(const void* g, void* l) {
  __builtin_amdgcn_global_load_lds(
      (const __attribute__((address_space(1))) unsigned int*)g,
      (__attribute__((address_space(3))) unsigned int*)l,
      16, 0, 0);
}

// fp32 -> bf16 bits, round-to-nearest-even
__device__ __forceinline__ unsigned short f2bf(float f) {
  unsigned int u = __builtin_bit_cast(unsigned int, f);
  u += 0x7FFFu + ((u >> 16) & 1u);
  return (unsigned short)(u >> 16);
}

// ---- K0: zero atomic accumulators (d_ws is poisoned 0xAA) ----
__global__ void k_zero(float* __restrict__ colsum, float* __restrict__ S,
                       int* __restrict__ cnt) {
  colsum[threadIdx.x] = 0.f;
  if (threadIdx.x == 0) { S[0] = 0.f; cnt[0] = 0; }
}

// ---- K1: one pass: bf16 convert (row-major) + row sq-norms + colsum/S atomics ----
// 256 blocks x 256 threads; block handles 32 rows, wave handles 8 rows
__global__ void k_prep(const float* __restrict__ src, const float* __restrict__ tgt,
                       unsigned short* __restrict__ Xb, float* __restrict__ sqv,
                       float* __restrict__ colsum, float* __restrict__ S) {
  __shared__ float colacc[256];
  __shared__ float wred[4];
  int t = threadIdx.x, l = t & 63, w = t >> 6;
  colacc[t] = 0.f;
  __syncthreads();
  int base = blockIdx.x * 32;
  float c0 = 0.f, c1 = 0.f, c2 = 0.f, c3 = 0.f;
  float wsq = 0.f;
  #pragma unroll
  for (int r = 0; r < 8; ++r) {
    int row = base + w * 8 + r;
    const float* p = (row < NS) ? (src + (size_t)row * D) : (tgt + (size_t)(row - NS) * D);
    float4 v = ((const float4*)p)[l];
    ushort4 bv;
    bv.x = f2bf(v.x); bv.y = f2bf(v.y); bv.z = f2bf(v.z); bv.w = f2bf(v.w);
    ((ushort4*)(Xb + (size_t)row * D))[l] = bv;
    c0 += v.x; c1 += v.y; c2 += v.z; c3 += v.w;
    float s = fmaf(v.x, v.x, fmaf(v.y, v.y, fmaf(v.z, v.z, v.w * v.w)));
    for (int o = 32; o > 0; o >>= 1) s += __shfl_down(s, o, 64);
    if (l == 0) { sqv[row] = s; wsq += s; }
  }
  atomicAdd(&colacc[4 * l + 0], c0);
  atomicAdd(&colacc[4 * l + 1], c1);
  atomicAdd(&colacc[4 * l + 2], c2);
  atomicAdd(&colacc[4 * l + 3], c3);
  if (l == 0) wred[w] = wsq;
  __syncthreads();
  atomicAdd(&colsum[t], colacc[t]);
  if (t == 0) atomicAdd(S, (wred[0] + wred[1]) + (wred[2] + wred[3]));
}

// ---- K2: finalize bandwidth in fp64 (cheap: 256 loads) ----
__global__ void k_bw(const float* __restrict__ colsum, const float* __restrict__ S,
                     float* __restrict__ coef) {
  __shared__ double red[256];
  int t = threadIdx.x;
  double c = (double)colsum[t];
  red[t] = c * c;
  __syncthreads();
  for (int s = 128; s > 0; s >>= 1) {
    if (t < s) red[t] += red[t + s];
    __syncthreads();
  }
  if (t == 0) {
    double msq = red[0];
    double Sv = (double)S[0];
    double n = (double)N_TOT;
    double sumL2 = 2.0 * n * Sv - 2.0 * msq;
    double bw = sumL2 / (n * n - n) / 4.0;        // / KERNEL_MUL**(KERNEL_NUM//2)
    double c4 = 1.0 / (bw * 16.0 + 1e-6);         // widest kernel (k=4)
    coef[0] = (float)(c4 * 1.4426950408889634);   // * log2(e) for exp2
  }
}

// ---- K3: upper-triangle 128x128 tiles, LDS-staged (round-2 structure) ----
__global__ __launch_bounds__(256) void k_main(
    const unsigned short* __restrict__ Xb, const float* __restrict__ sqv,
    const float* __restrict__ coef, float* __restrict__ bpart,
    int* __restrict__ cnt, float* __restrict__ out) {
  // triangular decode: block b -> (bi, bj), bi <= bj
  int b = blockIdx.x;
  int bi = (int)((2.f * NB + 1.f - sqrtf((float)((2 * NB + 1) * (2 * NB + 1) - 8 * b))) * 0.5f);
  if (bi < 0) bi = 0;
  if (bi > NB - 1) bi = NB - 1;
  while ((bi + 1) * (2 * NB - bi) / 2 <= b) ++bi;
  while (bi * (2 * NB - bi + 1) / 2 > b) --bi;
  int bj = bi + (b - bi * (2 * NB - bi + 1) / 2);

  __shared__ unsigned short ldsA[128 * 64];  // [row][kslot], 128B/row, xor-swizzled
  __shared__ unsigned short ldsB[128 * 64];
  __shared__ float sqA[128], sqB[128];
  __shared__ float redw[4];
  __shared__ double red[256];
  __shared__ int lastFlag;

  int t = threadIdx.x, l = t & 63, w = t >> 6;
  int lr = l & 31, half = l >> 5;
  int waveRow = w >> 1, waveCol = w & 1;

  if (t < 128) sqA[t] = sqv[bi * 128 + t];
  else         sqB[t - 128] = sqv[bj * 128 + (t - 128)];
  float A4 = coef[0];

  const unsigned short* arow = Xb + (size_t)bi * 128 * D;
  const unsigned short* brow = Xb + (size_t)bj * 128 * D;

  f32x16 acc[2][2] = {};

  for (int ko = 0; ko < 4; ++ko) {
    if (ko) __syncthreads();
    int kOff = ko * 64;
    #pragma unroll
    for (int p = 0; p < 4; ++p) {
      int seg = p * 256 + w * 64 + l;       // 16B segment id, 0..1023
      int row = seg >> 3;
      int kb = (seg & 7) ^ (row & 7);       // xor swizzle on the global source side
      int goff = row * D + kOff + kb * 8;
      gload16(arow + goff, &ldsA[(p * 4 + w) * 512]);
      gload16(brow + goff, &ldsB[(p * 4 + w) * 512]);
    }
    __syncthreads();
    #pragma unroll
    for (int ks = 0; ks < 4; ++ks) {
      int phys = (2 * ks + half) ^ (lr & 7);   // physical 16B slot after swizzle
      bf16x8 aF[2], bF[2];
      #pragma unroll
      for (int rb = 0; rb < 2; ++rb) {
        int rowA = waveRow * 64 + rb * 32 + lr;
        aF[rb] = *(const bf16x8*)&ldsA[rowA * 64 + phys * 8];
        int rowB = waveCol * 64 + rb * 32 + lr;
        bF[rb] = *(const bf16x8*)&ldsB[rowB * 64 + phys * 8];
      }
      #pragma unroll
      for (int rb = 0; rb < 2; ++rb)
        #pragma unroll
        for (int cb = 0; cb < 2; ++cb)
          acc[rb][cb] = __builtin_amdgcn_mfma_f32_32x32x16_bf16(aF[rb], bF[cb], acc[rb][cb], 0, 0, 0);
    }
  }

  // Packed epilogue: t = 2A4*dot - A4*sqi - A4*sqj ; e = exp2(t) (t<0)
  // sum5 = e+e^2+e^4+e^8+e^16.  float2 -> v_pk_fma_f32 / v_pk_mul_f32.
  // C/D layout (verified): col = lane&31, row = (r&3) + 8*(r>>2) + 4*(lane>>5)
  float c2A4 = 2.f * A4, nA4 = -A4;
  f32x2 lsum2 = {0.f, 0.f};
  bool diag = (bi == bj);
  #pragma unroll
  for (int cb = 0; cb < 2; ++cb) {
    int jj = waveCol * 64 + cb * 32 + lr;
    float bjv = nA4 * sqB[jj];
    #pragma unroll
    for (int rb = 0; rb < 2; ++rb) {
      #pragma unroll
      for (int r = 0; r < 16; r += 2) {
        int ii = waveRow * 64 + rb * 32 + (r & 3) + 8 * (r >> 2) + 4 * half;
        f32x2 dot2 = {acc[rb][cb][r], acc[rb][cb][r + 1]};
        f32x2 sq2 = {sqA[ii], sqA[ii + 1]};
        f32x2 tt = c2A4 * dot2 + (nA4 * sq2 + bjv);
        f32x2 e;
        e.x = __builtin_amdgcn_exp2f(tt.x);
        e.y = __builtin_amdgcn_exp2f(tt.y);
        f32x2 e2 = e * e, e4 = e2 * e2, e8 = e4 * e4, e16 = e8 * e8;
        f32x2 kern = ((e + e2) + (e4 + e8)) + e16;
        if (diag) {                          // block-uniform branch
          if (ii == jj) kern.x = 0.f;
          if (ii + 1 == jj) kern.y = 0.f;
        }
        lsum2 += kern;
      }
    }
  }
  float lsum = lsum2.x + lsum2.y;
  for (int o = 32; o > 0; o >>= 1) lsum += __shfl_down(lsum, o, 64);
  if (l == 0) redw[w] = lsum;
  __syncthreads();
  if (t == 0) {
    float tot = (redw[0] + redw[1]) + (redw[2] + redw[3]);
    float wgt = diag ? 1.f : 2.f;                               // symmetry weight
    float sgn = ((bi < HALF_B) == (bj < HALF_B)) ? 1.f : -1.f;  // s_i * s_j
    bpart[b] = tot * wgt * sgn;
    __threadfence();                                            // publish bpart[b]
    int old = atomicAdd(cnt, 1);
    lastFlag = (old == NTRI - 1);
  }
  __syncthreads();
  if (lastFlag) {                 // last block: final fp64 reduction
    __threadfence();              // acquire: all bpart writes visible
    double s = 0.0;
    for (int k = 0; k < 9; ++k) {
      int idx = k * 256 + t;
      if (idx < NTRI) s += (double)bpart[idx];
    }
    red[t] = s;
    __syncthreads();
    for (int st = 128; st > 0; st >>= 1) {
      if (t < st) red[t] += red[t + st];
      __syncthreads();
    }
    if (t == 0) {
      double total = red[0] + 5.0 * (double)N_TOT;  // diagonal: K_ii = 5, sign +1
      out[0] = (float)(total / ((double)NS * (double)NS));
    }
  }
}

extern "C" void kernel_launch(void* const* d_in, const int* in_sizes, int n_in,
                              void* d_out, int out_size, void* d_ws, size_t ws_size,
                              hipStream_t stream) {
  const float* src = (const float*)d_in[0];
  const float* tgt = (const float*)d_in[1];
  float* out = (float*)d_out;
  char* ws = (char*)d_ws;
  unsigned short* Xb = (unsigned short*)ws;                     // 4 MB bf16 row-major
  float* sqv   = (float*)(ws + (4u << 20));                     // 32 KB row sq-norms
  float* colsum = (float*)(ws + (4u << 20) + (32u << 10));      // 1 KB column sums
  float* S     = (float*)(ws + (4u << 20) + (33u << 10));       // 4 B
  float* coef  = (float*)(ws + (4u << 20) + (34u << 10));       // 4 B
  int*   cnt   = (int*)  (ws + (4u << 20) + (34u << 10) + 64);  // 4 B completion counter
  float* bpart = (float*)(ws + (4u << 20) + (35u << 10));       // 8.3 KB tile partials

  hipLaunchKernelGGL(k_zero, dim3(1), dim3(256), 0, stream, colsum, S, cnt);
  hipLaunchKernelGGL(k_prep, dim3(256), dim3(256), 0, stream, src, tgt, Xb, sqv, colsum, S);
  hipLaunchKernelGGL(k_bw, dim3(1), dim3(256), 0, stream, colsum, S, coef);
  hipLaunchKernelGGL(k_main, dim3(NTRI), dim3(256), 0, stream, Xb, sqv, coef, bpart, cnt, out);
}

// Round 5
// 105.456 us; speedup vs baseline: 1.2991x; 1.2293x over previous
//
#include <hip/hip_runtime.h>

#define N_TOT 8192
#define NS 4096
#define D 256
#define NB 64                 // 8192/128 tiles per dim
#define NTRI (NB*(NB+1)/2)    // 2080 upper-triangle tiles
#define HALF_B 32             // tiles per half (4096/128)

typedef float f32x16 __attribute__((ext_vector_type(16)));
typedef float f32x2 __attribute__((ext_vector_type(2)));
typedef short bf16x8 __attribute__((ext_vector_type(8)));

__device__ __forceinline__ void gload16(const void* g, void* l) {
  __builtin_amdgcn_global_load_lds(
      (const __attribute__((address_space(1))) unsigned int*)g,
      (__attribute__((address_space(3))) unsigned int*)l,
      16, 0, 0);
}

// fp32 -> bf16 bits, round-to-nearest-even
__device__ __forceinline__ unsigned short f2bf(float f) {
  unsigned int u = __builtin_bit_cast(unsigned int, f);
  u += 0x7FFFu + ((u >> 16) & 1u);
  return (unsigned short)(u >> 16);
}

// ---- K0: zero atomic accumulators (d_ws is poisoned 0xAA) ----
__global__ void k_zero(float* __restrict__ colsum, float* __restrict__ S) {
  colsum[threadIdx.x] = 0.f;
  if (threadIdx.x == 0) S[0] = 0.f;
}

// ---- K1: one pass: bf16 convert (row-major) + row sq-norms + colsum/S atomics ----
__global__ void k_prep(const float* __restrict__ src, const float* __restrict__ tgt,
                       unsigned short* __restrict__ Xb, float* __restrict__ sqv,
                       float* __restrict__ colsum, float* __restrict__ S) {
  __shared__ float colacc[256];
  __shared__ float wred[4];
  int t = threadIdx.x, l = t & 63, w = t >> 6;
  colacc[t] = 0.f;
  __syncthreads();
  int base = blockIdx.x * 32;
  float c0 = 0.f, c1 = 0.f, c2 = 0.f, c3 = 0.f;
  float wsq = 0.f;
  #pragma unroll
  for (int r = 0; r < 8; ++r) {
    int row = base + w * 8 + r;
    const float* p = (row < NS) ? (src + (size_t)row * D) : (tgt + (size_t)(row - NS) * D);
    float4 v = ((const float4*)p)[l];
    ushort4 bv;
    bv.x = f2bf(v.x); bv.y = f2bf(v.y); bv.z = f2bf(v.z); bv.w = f2bf(v.w);
    ((ushort4*)(Xb + (size_t)row * D))[l] = bv;
    c0 += v.x; c1 += v.y; c2 += v.z; c3 += v.w;
    float s = fmaf(v.x, v.x, fmaf(v.y, v.y, fmaf(v.z, v.z, v.w * v.w)));
    for (int o = 32; o > 0; o >>= 1) s += __shfl_down(s, o, 64);
    if (l == 0) { sqv[row] = s; wsq += s; }
  }
  atomicAdd(&colacc[4 * l + 0], c0);
  atomicAdd(&colacc[4 * l + 1], c1);
  atomicAdd(&colacc[4 * l + 2], c2);
  atomicAdd(&colacc[4 * l + 3], c3);
  if (l == 0) wred[w] = wsq;
  __syncthreads();
  atomicAdd(&colsum[t], colacc[t]);
  if (t == 0) atomicAdd(S, (wred[0] + wred[1]) + (wred[2] + wred[3]));
}

// ---- K2: finalize bandwidth in fp64 (256 loads, 1 block) ----
__global__ void k_bw(const float* __restrict__ colsum, const float* __restrict__ S,
                     float* __restrict__ coef) {
  __shared__ double red[256];
  int t = threadIdx.x;
  double c = (double)colsum[t];
  red[t] = c * c;
  __syncthreads();
  for (int s = 128; s > 0; s >>= 1) {
    if (t < s) red[t] += red[t + s];
    __syncthreads();
  }
  if (t == 0) {
    double msq = red[0];
    double Sv = (double)S[0];
    double n = (double)N_TOT;
    double sumL2 = 2.0 * n * Sv - 2.0 * msq;
    double bw = sumL2 / (n * n - n) / 4.0;        // / KERNEL_MUL**(KERNEL_NUM//2)
    double c4 = 1.0 / (bw * 16.0 + 1e-6);         // widest kernel (k=4)
    coef[0] = (float)(c4 * 1.4426950408889634);   // * log2(e) for exp2
  }
}

// ---- K3: upper-triangle 128x128 tiles, LDS-staged; NO device fence / atomics ----
// (round-4 lesson: per-block __threadfence = agent-scope L2 writeback+inv on
//  gfx950 -> evicts the L2-resident Xb working set, +21us. Keep k_main pure.)
__global__ __launch_bounds__(256) void k_main(
    const unsigned short* __restrict__ Xb, const float* __restrict__ sqv,
    const float* __restrict__ coef, float* __restrict__ bpart) {
  // triangular decode: block b -> (bi, bj), bi <= bj
  int b = blockIdx.x;
  int bi = (int)((2.f * NB + 1.f - sqrtf((float)((2 * NB + 1) * (2 * NB + 1) - 8 * b))) * 0.5f);
  if (bi < 0) bi = 0;
  if (bi > NB - 1) bi = NB - 1;
  while ((bi + 1) * (2 * NB - bi) / 2 <= b) ++bi;
  while (bi * (2 * NB - bi + 1) / 2 > b) --bi;
  int bj = bi + (b - bi * (2 * NB - bi + 1) / 2);

  __shared__ unsigned short ldsA[128 * 64];  // [row][kslot], 128B/row, xor-swizzled
  __shared__ unsigned short ldsB[128 * 64];
  __shared__ float sqA[128], sqB[128];
  __shared__ float redw[4];

  int t = threadIdx.x, l = t & 63, w = t >> 6;
  int lr = l & 31, half = l >> 5;
  int waveRow = w >> 1, waveCol = w & 1;

  if (t < 128) sqA[t] = sqv[bi * 128 + t];
  else         sqB[t - 128] = sqv[bj * 128 + (t - 128)];
  float A4 = coef[0];

  const unsigned short* arow = Xb + (size_t)bi * 128 * D;
  const unsigned short* brow = Xb + (size_t)bj * 128 * D;

  f32x16 acc[2][2] = {};

  for (int ko = 0; ko < 4; ++ko) {
    if (ko) __syncthreads();
    int kOff = ko * 64;
    #pragma unroll
    for (int p = 0; p < 4; ++p) {
      int seg = p * 256 + w * 64 + l;       // 16B segment id, 0..1023
      int row = seg >> 3;
      int kb = (seg & 7) ^ (row & 7);       // xor swizzle on the global source side
      int goff = row * D + kOff + kb * 8;
      gload16(arow + goff, &ldsA[(p * 4 + w) * 512]);
      gload16(brow + goff, &ldsB[(p * 4 + w) * 512]);
    }
    __syncthreads();
    #pragma unroll
    for (int ks = 0; ks < 4; ++ks) {
      int phys = (2 * ks + half) ^ (lr & 7);   // physical 16B slot after swizzle
      bf16x8 aF[2], bF[2];
      #pragma unroll
      for (int rb = 0; rb < 2; ++rb) {
        int rowA = waveRow * 64 + rb * 32 + lr;
        aF[rb] = *(const bf16x8*)&ldsA[rowA * 64 + phys * 8];
        int rowB = waveCol * 64 + rb * 32 + lr;
        bF[rb] = *(const bf16x8*)&ldsB[rowB * 64 + phys * 8];
      }
      #pragma unroll
      for (int rb = 0; rb < 2; ++rb)
        #pragma unroll
        for (int cb = 0; cb < 2; ++cb)
          acc[rb][cb] = __builtin_amdgcn_mfma_f32_32x32x16_bf16(aF[rb], bF[cb], acc[rb][cb], 0, 0, 0);
    }
  }

  // Packed epilogue: t = 2A4*dot - A4*sqi - A4*sqj ; e = exp2(t)
  // sum5 = e+e^2+e^4+e^8+e^16 (exp-squaring; bw_k = bw*2^k exactly)
  // C/D layout (verified): col = lane&31, row = (r&3) + 8*(r>>2) + 4*(lane>>5)
  float c2A4 = 2.f * A4, nA4 = -A4;
  f32x2 lsum2 = {0.f, 0.f};
  bool diag = (bi == bj);
  #pragma unroll
  for (int cb = 0; cb < 2; ++cb) {
    int jj = waveCol * 64 + cb * 32 + lr;
    float bjv = nA4 * sqB[jj];
    #pragma unroll
    for (int rb = 0; rb < 2; ++rb) {
      #pragma unroll
      for (int r = 0; r < 16; r += 2) {
        int ii = waveRow * 64 + rb * 32 + (r & 3) + 8 * (r >> 2) + 4 * half;
        f32x2 dot2 = {acc[rb][cb][r], acc[rb][cb][r + 1]};
        f32x2 sq2 = {sqA[ii], sqA[ii + 1]};
        f32x2 tt = c2A4 * dot2 + (nA4 * sq2 + bjv);
        f32x2 e;
        e.x = __builtin_amdgcn_exp2f(tt.x);
        e.y = __builtin_amdgcn_exp2f(tt.y);
        f32x2 e2 = e * e, e4 = e2 * e2, e8 = e4 * e4, e16 = e8 * e8;
        f32x2 kern = ((e + e2) + (e4 + e8)) + e16;
        if (diag) {                          // block-uniform branch
          if (ii == jj) kern.x = 0.f;
          if (ii + 1 == jj) kern.y = 0.f;
        }
        lsum2 += kern;
      }
    }
  }
  float lsum = lsum2.x + lsum2.y;
  for (int o = 32; o > 0; o >>= 1) lsum += __shfl_down(lsum, o, 64);
  if (l == 0) redw[w] = lsum;
  __syncthreads();
  if (t == 0) {
    float tot = (redw[0] + redw[1]) + (redw[2] + redw[3]);
    float wgt = diag ? 1.f : 2.f;                               // symmetry weight
    float sgn = ((bi < HALF_B) == (bj < HALF_B)) ? 1.f : -1.f;  // s_i * s_j
    bpart[b] = tot * wgt * sgn;
  }
}

// ---- K4: final fp64 reduction + analytic diagonal + mean ----
__global__ void k_final(const float* __restrict__ bpart, float* __restrict__ out) {
  __shared__ double red[256];
  int t = threadIdx.x;
  double s = 0.0;
  for (int k = 0; k < 9; ++k) {
    int idx = k * 256 + t;
    if (idx < NTRI) s += (double)bpart[idx];
  }
  red[t] = s;
  __syncthreads();
  for (int st = 128; st > 0; st >>= 1) {
    if (t < st) red[t] += red[t + st];
    __syncthreads();
  }
  if (t == 0) {
    double total = red[0] + 5.0 * (double)N_TOT;  // diagonal: K_ii = 5, sign +1
    out[0] = (float)(total / ((double)NS * (double)NS));
  }
}

extern "C" void kernel_launch(void* const* d_in, const int* in_sizes, int n_in,
                              void* d_out, int out_size, void* d_ws, size_t ws_size,
                              hipStream_t stream) {
  const float* src = (const float*)d_in[0];
  const float* tgt = (const float*)d_in[1];
  float* out = (float*)d_out;
  char* ws = (char*)d_ws;
  unsigned short* Xb = (unsigned short*)ws;                     // 4 MB bf16 row-major
  float* sqv   = (float*)(ws + (4u << 20));                     // 32 KB row sq-norms
  float* colsum = (float*)(ws + (4u << 20) + (32u << 10));      // 1 KB column sums
  float* S     = (float*)(ws + (4u << 20) + (33u << 10));       // 4 B
  float* coef  = (float*)(ws + (4u << 20) + (34u << 10));       // 4 B
  float* bpart = (float*)(ws + (4u << 20) + (35u << 10));       // 8.3 KB tile partials

  hipLaunchKernelGGL(k_zero, dim3(1), dim3(256), 0, stream, colsum, S);
  hipLaunchKernelGGL(k_prep, dim3(256), dim3(256), 0, stream, src, tgt, Xb, sqv, colsum, S);
  hipLaunchKernelGGL(k_bw, dim3(1), dim3(256), 0, stream, colsum, S, coef);
  hipLaunchKernelGGL(k_main, dim3(NTRI), dim3(256), 0, stream, Xb, sqv, coef, bpart);
  hipLaunchKernelGGL(k_final, dim3(1), dim3(256), 0, stream, bpart, out);
}